// Round 3
// baseline (5991.967 us; speedup 1.0000x reference)
//
#include <hip/hip_runtime.h>
#include <math.h>

#define THR  0.05f
#define BETA 0.9181805491303656f
#define B_SZ 64
#define T_STEPS 25

__device__ __forceinline__ float sigf(float x) { return 1.0f / (1.0f + __expf(-x)); }
__device__ __forceinline__ float tanh_fast(float x) {
    const float xc = fminf(fmaxf(x, -10.0f), 10.0f);
    const float e = __expf(2.0f * xc);
    return (e - 1.0f) / (e + 1.0f);
}

// ---------------------------------------------------------------------------
// Repack conv weights from (4*Ch, CIN, 3, 3) [OIHW] to [ci*9+tap][gate][c].
// ---------------------------------------------------------------------------
__global__ __launch_bounds__(256) void repack_kernel(
    const float* __restrict__ wt, float* __restrict__ wr, int Ch, int CIN)
{
    const int n = 4 * Ch * CIN * 9;
    for (int i = blockIdx.x * 256 + threadIdx.x; i < n; i += gridDim.x * 256) {
        const int c  = i % Ch;
        const int g  = (i / Ch) % 4;
        const int ct = i / (4 * Ch);      // ci*9 + tap
        wr[i] = wt[(size_t)(g * Ch + c) * (CIN * 9) + ct];
    }
}

// ---------------------------------------------------------------------------
// Fused ConvLSTM step. Input tile (cat(x|pooled-spike, mem)) staged in LDS
// with zero-padded halo. Thread computes P=4 consecutive pixels for one c.
// Per ci: 6 LDS strip floats x3 rows + 36 coalesced weight loads + 144 FMA.
// ---------------------------------------------------------------------------
template<int Cin, int Ch, int H, int W, int R, int CSPLIT, bool POOL_IN, int MINW>
__global__ __launch_bounds__(256, MINW) void conv_lstm(
    const float* __restrict__ xin,    // raw (B,Cin,H,W) or prev mem (B,Cin,2H,2W)
    const float* __restrict__ memin,  // (B,Ch,H,W)
    const float* __restrict__ synin,
    float* __restrict__ synout,
    float* __restrict__ memout,
    const float* __restrict__ wr,     // repacked [CIN*9][4][Ch]
    const float* __restrict__ bias)   // (4*Ch)
{
    constexpr int P = 4;
    constexpr int CIN = Cin + Ch;
    constexpr int SW = W + 4;
    constexpr int R2 = R + 2;
    constexpr int ChB = Ch / CSPLIT;
    constexpr int NREST = 256 / ChB;
    constexpr int COMBOS = R * (W / P);
    static_assert(256 % ChB == 0, "");
    static_assert(W % P == 0, "");
    static_assert(NREST <= COMBOS, "idle threads");
    static_assert(COMBOS % NREST == 0, "");

    __shared__ float tile[CIN * R2 * SW];

    const int tid = threadIdx.x;
    const int bid = blockIdx.x;
    const int cs = bid % CSPLIT;
    const int rs = (bid / CSPLIT) % (H / R);
    const int b  = bid / (CSPLIT * (H / R));
    const int r0 = rs * R;
    const int c0 = cs * ChB;

    for (int i = tid; i < CIN * R2 * SW; i += 256) tile[i] = 0.0f;
    __syncthreads();

    for (int i = tid; i < CIN * R2 * W; i += 256) {
        const int wx = i % W;
        const int ry = (i / W) % R2;
        const int ci = i / (W * R2);
        const int gy = r0 + ry - 1;
        if (gy < 0 || gy >= H) continue;
        float v;
        if (POOL_IN && ci < Cin) {
            const float* mp = xin + (((size_t)b * Cin + ci) * (2 * H) + 2 * gy) * (2 * W) + 2 * wx;
            const float mx = fmaxf(fmaxf(mp[0], mp[1]), fmaxf(mp[2 * W], mp[2 * W + 1]));
            v = (mx - THR) > 0.0f ? 1.0f : 0.0f;
        } else if (ci < Cin) {
            v = xin[(((size_t)b * Cin + ci) * H + gy) * W + wx];
        } else {
            v = memin[(((size_t)b * Ch + (ci - Cin)) * H + gy) * W + wx];
        }
        tile[(ci * R2 + ry) * SW + wx + 1] = v;
    }
    __syncthreads();

    const int c_sub = tid % ChB;
    const int rest  = tid / ChB;
    const int c = c0 + c_sub;

    const float b_i = bias[c];
    const float b_f = bias[c + Ch];
    const float b_g = bias[c + 2 * Ch];
    const float b_o = bias[c + 3 * Ch];

    for (int task = rest; task < COMBOS; task += NREST) {
        const int wg = task % (W / P);
        const int rl = task / (W / P);
        const int x0 = wg * P;
        const int gr = r0 + rl;

        float gi[P], gf[P], gg[P], go[P];
        #pragma unroll
        for (int p = 0; p < P; ++p) { gi[p] = b_i; gf[p] = b_f; gg[p] = b_g; go[p] = b_o; }

        #pragma unroll 2
        for (int ci = 0; ci < CIN; ++ci) {
            float s[3][P + 2];
            #pragma unroll
            for (int dy = 0; dy < 3; ++dy) {
                const float* rp = &tile[(ci * R2 + rl + dy) * SW + x0];
                const float4 a  = *(const float4*)rp;
                const float2 e  = *(const float2*)(rp + 4);
                s[dy][0] = a.x; s[dy][1] = a.y; s[dy][2] = a.z; s[dy][3] = a.w;
                s[dy][4] = e.x; s[dy][5] = e.y;
            }
            const float* wp = wr + (size_t)ci * 36 * Ch + c;
            #pragma unroll
            for (int tap = 0; tap < 9; ++tap) {
                const float wi  = wp[(tap * 4 + 0) * Ch];
                const float wf  = wp[(tap * 4 + 1) * Ch];
                const float wg_ = wp[(tap * 4 + 2) * Ch];
                const float wo  = wp[(tap * 4 + 3) * Ch];
                const int dy = tap / 3, dx = tap % 3;
                #pragma unroll
                for (int p = 0; p < P; ++p) {
                    const float v = s[dy][p + dx];
                    gi[p] = fmaf(v, wi, gi[p]);
                    gf[p] = fmaf(v, wf, gf[p]);
                    gg[p] = fmaf(v, wg_, gg[p]);
                    go[p] = fmaf(v, wo, go[p]);
                }
            }
        }

        const size_t base = (((size_t)b * Ch + c) * H + gr) * W + x0;
        const float4 synv = *(const float4*)(synin + base);
        const float sv[P] = {synv.x, synv.y, synv.z, synv.w};
        float so[P], mo[P];
        #pragma unroll
        for (int p = 0; p < P; ++p) {
            const float syn = sigf(gf[p]) * sv[p] + sigf(gi[p]) * tanh_fast(gg[p]);
            so[p] = syn;
            mo[p] = sigf(go[p]) * tanh_fast(syn);
        }
        *(float4*)(synout + base) = make_float4(so[0], so[1], so[2], so[3]);
        *(float4*)(memout + base) = make_float4(mo[0], mo[1], mo[2], mo[3]);
    }
}

// ---------------------------------------------------------------------------
// Fused maxpool(m3) -> spk3 -> cur4 = spk3 @ fc1_w.T + b -> Leaky(mem4).
// Wave computes 8 outputs; K=2048 via float4; pooling done inline from m3.
// ---------------------------------------------------------------------------
__global__ __launch_bounds__(256) void fc1_pool_kernel(
    const float* __restrict__ m3,    // (B, 64, 4, 32) membrane of layer 3
    const float* __restrict__ wt,    // (512, 2048)
    const float* __restrict__ bias,
    float* __restrict__ mem4,        // (B, 512)
    float* __restrict__ spk4)        // (B, 512)
{
    const int wid = (blockIdx.x * 256 + threadIdx.x) >> 6;
    const int lane = threadIdx.x & 63;
    const int og = wid & 63;
    const int b = wid >> 6;
    const int o0 = og * 8;

    float acc[8] = {0, 0, 0, 0, 0, 0, 0, 0};
    for (int it = 0; it < 8; ++it) {
        const int k = (it * 64 + lane) * 4;       // flat spk3 index, 4 at a time
        const int c = k >> 5;                      // 32 pooled px per channel (2x16)
        const int rem = k & 31;
        const int ph = rem >> 4;
        const int pw = rem & 15;                   // multiple of 4
        const float* mp = m3 + (((size_t)b * 64 + c) * 4 + 2 * ph) * 32 + 2 * pw;
        const float4 r0 = *(const float4*)mp;
        const float4 r1 = *(const float4*)(mp + 4);
        const float4 q0 = *(const float4*)(mp + 32);
        const float4 q1 = *(const float4*)(mp + 36);
        float4 sv;
        sv.x = ((fmaxf(fmaxf(r0.x, r0.y), fmaxf(q0.x, q0.y)) - THR) > 0.0f) ? 1.0f : 0.0f;
        sv.y = ((fmaxf(fmaxf(r0.z, r0.w), fmaxf(q0.z, q0.w)) - THR) > 0.0f) ? 1.0f : 0.0f;
        sv.z = ((fmaxf(fmaxf(r1.x, r1.y), fmaxf(q1.x, q1.y)) - THR) > 0.0f) ? 1.0f : 0.0f;
        sv.w = ((fmaxf(fmaxf(r1.z, r1.w), fmaxf(q1.z, q1.w)) - THR) > 0.0f) ? 1.0f : 0.0f;
        #pragma unroll
        for (int j = 0; j < 8; ++j) {
            const float4 wv = *(const float4*)(wt + (size_t)(o0 + j) * 2048 + k);
            acc[j] = fmaf(sv.x, wv.x, acc[j]);
            acc[j] = fmaf(sv.y, wv.y, acc[j]);
            acc[j] = fmaf(sv.z, wv.z, acc[j]);
            acc[j] = fmaf(sv.w, wv.w, acc[j]);
        }
    }
    float mine = 0.0f;
    #pragma unroll
    for (int j = 0; j < 8; ++j) {
        float a = acc[j];
        #pragma unroll
        for (int off = 32; off; off >>= 1) a += __shfl_xor(a, off, 64);
        if (lane == j) mine = a;
    }
    if (lane < 8) {
        const int o = o0 + lane;
        const float cur = mine + bias[o];
        const int i4 = b * 512 + o;
        float m = mem4[i4];
        const float reset = (m > THR) ? 1.0f : 0.0f;
        m = BETA * m + cur - reset * THR;
        spk4[i4] = ((m - THR) > 0.0f) ? 1.0f : 0.0f;
        mem4[i4] = m;
    }
}

// ---------------------------------------------------------------------------
// cur5 = spk4 @ fc2_w.T + fc2_b; Leaky(mem5); writes spk_rec[t], mem_rec[t].
// ---------------------------------------------------------------------------
__global__ __launch_bounds__(256) void fc2_kernel(
    const float* __restrict__ spk4,
    const float* __restrict__ wt,
    const float* __restrict__ bias,
    float* __restrict__ mem5,
    float* __restrict__ out_spk,
    float* __restrict__ out_mem)
{
    const int wid = (blockIdx.x * 256 + threadIdx.x) >> 6;
    const int lane = threadIdx.x & 63;
    if (wid >= 2 * B_SZ) return;
    const int o = wid & 1;
    const int b = wid >> 1;
    const float* wr = wt + (size_t)o * 512;
    const float* sr = spk4 + (size_t)b * 512;
    float acc = 0.0f;
    #pragma unroll
    for (int i = 0; i < 8; ++i)
        acc = fmaf(sr[lane + i * 64], wr[lane + i * 64], acc);
    #pragma unroll
    for (int off = 32; off; off >>= 1) acc += __shfl_down(acc, off, 64);
    if (lane == 0) {
        const float cur = acc + bias[o];
        const int i5 = b * 2 + o;
        float m = mem5[i5];
        const float reset = (m > THR) ? 1.0f : 0.0f;
        m = BETA * m + cur - reset * THR;
        out_spk[i5] = ((m - THR) > 0.0f) ? 1.0f : 0.0f;
        out_mem[i5] = m;
        mem5[i5] = m;
    }
}

extern "C" void kernel_launch(void* const* d_in, const int* in_sizes, int n_in,
                              void* d_out, int out_size, void* d_ws, size_t ws_size,
                              hipStream_t stream) {
    (void)in_sizes; (void)n_in; (void)out_size; (void)ws_size;

    const float* x    = (const float*)d_in[0];
    const float* w1   = (const float*)d_in[1];
    const float* b1   = (const float*)d_in[2];
    const float* w2   = (const float*)d_in[3];
    const float* b2   = (const float*)d_in[4];
    const float* w3   = (const float*)d_in[5];
    const float* b3   = (const float*)d_in[6];
    const float* fc1w = (const float*)d_in[7];
    const float* fc1b = (const float*)d_in[8];
    const float* fc2w = (const float*)d_in[9];
    const float* fc2b = (const float*)d_in[10];

    float* out = (float*)d_out;
    float* ws = (float*)d_ws;

    const size_t N1 = (size_t)B_SZ * 16 * 16 * 128;
    const size_t N2 = (size_t)B_SZ * 32 * 8 * 64;
    const size_t N3 = (size_t)B_SZ * 64 * 4 * 32;

    size_t off = 0;
    float* syn1  = ws + off; off += N1;
    float* mem1a = ws + off; off += N1;
    float* mem1b = ws + off; off += N1;
    float* syn2  = ws + off; off += N2;
    float* mem2a = ws + off; off += N2;
    float* mem2b = ws + off; off += N2;
    float* syn3  = ws + off; off += N3;
    float* mem3a = ws + off; off += N3;
    float* mem3b = ws + off; off += N3;
    float* mem4  = ws + off; off += (size_t)B_SZ * 512;
    float* mem5  = ws + off; off += (size_t)B_SZ * 2;
    const size_t zero_elems = off;
    float* spk4 = ws + off; off += (size_t)B_SZ * 512;
    float* wr1  = ws + off; off += (size_t)64 * 17 * 9;
    float* wr2  = ws + off; off += (size_t)128 * 48 * 9;
    float* wr3  = ws + off; off += (size_t)256 * 96 * 9;

    hipMemsetAsync(d_ws, 0, zero_elems * sizeof(float), stream);

    repack_kernel<<<64, 256, 0, stream>>>(w1, wr1, 16, 17);
    repack_kernel<<<64, 256, 0, stream>>>(w2, wr2, 32, 48);
    repack_kernel<<<64, 256, 0, stream>>>(w3, wr3, 64, 96);

    float* m1r = mem1a; float* m1w = mem1b;
    float* m2r = mem2a; float* m2w = mem2b;
    float* m3r = mem3a; float* m3w = mem3b;

    for (int t = 0; t < T_STEPS; ++t) {
        const float* xt = x + (size_t)t * B_SZ * 16 * 128;

        // L1: R=1, CSPLIT=1 -> grid 64*16 = 1024, LDS 26.9 KB, 4 blocks/CU
        conv_lstm<1, 16, 16, 128, 1, 1, false, 4><<<1024, 256, 0, stream>>>(
            xt, m1r, syn1, syn1, m1w, wr1, b1);
        // L2: R=1, CSPLIT=2 -> grid 64*8*2 = 1024, LDS 39.2 KB, 4 blocks/CU
        conv_lstm<16, 32, 8, 64, 1, 2, true, 4><<<1024, 256, 0, stream>>>(
            m1w, m2r, syn2, syn2, m2w, wr2, b2);
        // L3: R=1, CSPLIT=2 -> grid 64*4*2 = 512, LDS 41.5 KB, 2 blocks/CU
        conv_lstm<32, 64, 4, 32, 1, 2, true, 2><<<512, 256, 0, stream>>>(
            m2w, m3r, syn3, syn3, m3w, wr3, b3);

        fc1_pool_kernel<<<1024, 256, 0, stream>>>(m3w, fc1w, fc1b, mem4, spk4);
        fc2_kernel<<<32, 256, 0, stream>>>(
            spk4, fc2w, fc2b, mem5, out + (size_t)t * 2 * B_SZ,
            out + 3200 + (size_t)t * 2 * B_SZ);

        float* tmp;
        tmp = m1r; m1r = m1w; m1w = tmp;
        tmp = m2r; m2r = m2w; m2w = tmp;
        tmp = m3r; m3r = m3w; m3w = tmp;
    }
}

// Round 4
// 4787.990 us; speedup vs baseline: 1.2515x; 1.2515x over previous
//
#include <hip/hip_runtime.h>
#include <math.h>

#define THR  0.05f
#define BETA 0.9181805491303656f
#define B_SZ 64
#define T_STEPS 25

__device__ __forceinline__ float sigf(float x) { return 1.0f / (1.0f + __expf(-x)); }
__device__ __forceinline__ float tanh_fast(float x) {
    const float xc = fminf(fmaxf(x, -10.0f), 10.0f);
    const float e = __expf(2.0f * xc);
    return (e - 1.0f) / (e + 1.0f);
}

// ---------------------------------------------------------------------------
// Repack conv weights from (4*Ch, CIN, 3, 3) [OIHW] to [c][ci][tap][gate]
// so each (c, ci)'s 36 gate-tap weights are CONSECUTIVE -> scalar s_load path.
// ---------------------------------------------------------------------------
__global__ __launch_bounds__(256) void repack_kernel(
    const float* __restrict__ wt, float* __restrict__ wr, int Ch, int CIN)
{
    const int n = 4 * Ch * CIN * 9;
    for (int i = blockIdx.x * 256 + threadIdx.x; i < n; i += gridDim.x * 256) {
        const int g   = i & 3;
        const int tap = (i >> 2) % 9;
        const int ci  = (i / 36) % CIN;
        const int c   = i / (36 * CIN);
        wr[i] = wt[(((size_t)(g * Ch + c)) * CIN + ci) * 9 + tap];
    }
}

// ---------------------------------------------------------------------------
// Fused ConvLSTM step, wave-per-channel / lanes-per-pixel layout.
// Wave handles channel c (uniform) -> weights via SGPR s_load (zero VMEM in
// the inner loop). Lanes cover R rows x W/2 pixel-pairs. Input tile staged
// in LDS in ci-chunks (<=28KB) so grid=1024 runs 4 blocks/CU.
// ---------------------------------------------------------------------------
template<int Cin, int Ch, int H, int W, int R, int CSPLIT, int CHUNK, bool POOL_IN>
__global__ __launch_bounds__(256, 4) void conv_lstm(
    const float* __restrict__ xin,    // raw (B,Cin,H,W) or prev mem (B,Cin,2H,2W)
    const float* __restrict__ memin,  // (B,Ch,H,W)
    const float* __restrict__ synin,
    float* __restrict__ synout,
    float* __restrict__ memout,
    const float* __restrict__ wr,     // repacked [c][ci][tap][gate]
    const float* __restrict__ bias)   // (4*Ch)
{
    constexpr int CIN = Cin + Ch;
    constexpr int R2 = R + 2;
    constexpr int SW = W + 4;
    constexpr int ROWLANES = W / 2;
    constexpr int NROUNDS = CIN / CHUNK;
    constexpr int CITERS = Ch / (CSPLIT * 4);
    static_assert(R * ROWLANES == 64, "wave must cover R x W/2 pixel pairs");
    static_assert(CIN % CHUNK == 0, "");
    static_assert(CITERS >= 1, "");

    __shared__ float tile[CHUNK * R2 * SW];

    const int tid = threadIdx.x;
    const int bid = blockIdx.x;
    const int cs = bid % CSPLIT;
    const int rs = (bid / CSPLIT) % (H / R);
    const int b  = bid / (CSPLIT * (H / R));
    const int r0 = rs * R;
    const int c0 = cs * (Ch / CSPLIT);

    const int lane = tid & 63;
    const int wid  = tid >> 6;
    const int ly   = lane / ROWLANES;         // local row 0..R-1
    const int lx   = 2 * (lane % ROWLANES);   // x0 (even)
    const int gy_out = r0 + ly;

    // wave-uniform channel ids + weight bases (forces SGPR/scalar-load path)
    int cu[CITERS];
    #pragma unroll
    for (int k = 0; k < CITERS; ++k)
        cu[k] = __builtin_amdgcn_readfirstlane(c0 + k * 4 + wid);

    // accumulators: acc[k][gate*2 + p], gates i,f,g,o
    float acc[CITERS][8];
    #pragma unroll
    for (int k = 0; k < CITERS; ++k) {
        const float bi = bias[cu[k]];
        const float bf = bias[cu[k] + Ch];
        const float bg = bias[cu[k] + 2 * Ch];
        const float bo = bias[cu[k] + 3 * Ch];
        acc[k][0] = bi; acc[k][1] = bi;
        acc[k][2] = bf; acc[k][3] = bf;
        acc[k][4] = bg; acc[k][5] = bg;
        acc[k][6] = bo; acc[k][7] = bo;
    }

    for (int rd = 0; rd < NROUNDS; ++rd) {
        const int k0 = rd * CHUNK;
        if (rd) __syncthreads();

        // stage chunk [k0, k0+CHUNK) with zero-padded halo, single pass
        for (int i = tid; i < CHUNK * R2 * SW; i += 256) {
            const int col = i % SW;
            const int ry  = (i / SW) % R2;
            const int cil = i / (SW * R2);
            const int ci  = k0 + cil;
            const int x   = col - 1;
            const int gy  = r0 + ry - 1;
            float v = 0.0f;
            if (x >= 0 && x < W && gy >= 0 && gy < H) {
                if (POOL_IN && ci < Cin) {
                    const float* mp = xin + (((size_t)b * Cin + ci) * (2 * H) + 2 * gy) * (2 * W) + 2 * x;
                    const float mx = fmaxf(fmaxf(mp[0], mp[1]), fmaxf(mp[2 * W], mp[2 * W + 1]));
                    v = (mx - THR) > 0.0f ? 1.0f : 0.0f;
                } else if (ci < Cin) {
                    v = xin[(((size_t)b * Cin + ci) * H + gy) * W + x];
                } else {
                    v = memin[(((size_t)b * Ch + (ci - Cin)) * H + gy) * W + x];
                }
            }
            tile[i] = v;
        }
        __syncthreads();

        for (int cil = 0; cil < CHUNK; ++cil) {
            // 4-wide strips for pixel pair, 3 rows: 6x ds_read_b64
            float s[3][4];
            #pragma unroll
            for (int dy = 0; dy < 3; ++dy) {
                const float* rp = &tile[(cil * R2 + ly + dy) * SW + lx];
                const float2 a = *(const float2*)rp;
                const float2 bq = *(const float2*)(rp + 2);
                s[dy][0] = a.x; s[dy][1] = a.y; s[dy][2] = bq.x; s[dy][3] = bq.y;
            }
            #pragma unroll
            for (int k = 0; k < CITERS; ++k) {
                // uniform address -> s_load of 36 consecutive floats
                const float* wp = wr + ((size_t)cu[k] * CIN + (k0 + cil)) * 36;
                #pragma unroll
                for (int tap = 0; tap < 9; ++tap) {
                    const int dy = tap / 3, dx = tap % 3;
                    const float wi  = wp[tap * 4 + 0];
                    const float wf  = wp[tap * 4 + 1];
                    const float wg_ = wp[tap * 4 + 2];
                    const float wo  = wp[tap * 4 + 3];
                    #pragma unroll
                    for (int p = 0; p < 2; ++p) {
                        const float v = s[dy][p + dx];
                        acc[k][0 + p] = fmaf(v, wi,  acc[k][0 + p]);
                        acc[k][2 + p] = fmaf(v, wf,  acc[k][2 + p]);
                        acc[k][4 + p] = fmaf(v, wg_, acc[k][4 + p]);
                        acc[k][6 + p] = fmaf(v, wo,  acc[k][6 + p]);
                    }
                }
            }
        }
    }

    // epilogue: LSTM state update, pixel-pair vectorized
    #pragma unroll
    for (int k = 0; k < CITERS; ++k) {
        const int c = c0 + k * 4 + wid;
        const size_t base = (((size_t)b * Ch + c) * H + gy_out) * W + lx;
        const float2 synv = *(const float2*)(synin + base);
        float sv[2] = {synv.x, synv.y};
        float so[2], mo[2];
        #pragma unroll
        for (int p = 0; p < 2; ++p) {
            const float syn = sigf(acc[k][2 + p]) * sv[p] + sigf(acc[k][0 + p]) * tanh_fast(acc[k][4 + p]);
            so[p] = syn;
            mo[p] = sigf(acc[k][6 + p]) * tanh_fast(syn);
        }
        *(float2*)(synout + base) = make_float2(so[0], so[1]);
        *(float2*)(memout + base) = make_float2(mo[0], mo[1]);
    }
}

// ---------------------------------------------------------------------------
// Fused maxpool(m3) -> spk3 -> cur4 = spk3 @ fc1_w.T + b -> Leaky(mem4).
// ---------------------------------------------------------------------------
__global__ __launch_bounds__(256) void fc1_pool_kernel(
    const float* __restrict__ m3,    // (B, 64, 4, 32)
    const float* __restrict__ wt,    // (512, 2048)
    const float* __restrict__ bias,
    float* __restrict__ mem4,
    float* __restrict__ spk4)
{
    const int wid = (blockIdx.x * 256 + threadIdx.x) >> 6;
    const int lane = threadIdx.x & 63;
    const int og = wid & 63;
    const int b = wid >> 6;
    const int o0 = og * 8;

    float acc[8] = {0, 0, 0, 0, 0, 0, 0, 0};
    for (int it = 0; it < 8; ++it) {
        const int k = (it * 64 + lane) * 4;
        const int c = k >> 5;
        const int rem = k & 31;
        const int ph = rem >> 4;
        const int pw = rem & 15;
        const float* mp = m3 + (((size_t)b * 64 + c) * 4 + 2 * ph) * 32 + 2 * pw;
        const float4 r0 = *(const float4*)mp;
        const float4 r1 = *(const float4*)(mp + 4);
        const float4 q0 = *(const float4*)(mp + 32);
        const float4 q1 = *(const float4*)(mp + 36);
        float4 sv;
        sv.x = ((fmaxf(fmaxf(r0.x, r0.y), fmaxf(q0.x, q0.y)) - THR) > 0.0f) ? 1.0f : 0.0f;
        sv.y = ((fmaxf(fmaxf(r0.z, r0.w), fmaxf(q0.z, q0.w)) - THR) > 0.0f) ? 1.0f : 0.0f;
        sv.z = ((fmaxf(fmaxf(r1.x, r1.y), fmaxf(q1.x, q1.y)) - THR) > 0.0f) ? 1.0f : 0.0f;
        sv.w = ((fmaxf(fmaxf(r1.z, r1.w), fmaxf(q1.z, q1.w)) - THR) > 0.0f) ? 1.0f : 0.0f;
        #pragma unroll
        for (int j = 0; j < 8; ++j) {
            const float4 wv = *(const float4*)(wt + (size_t)(o0 + j) * 2048 + k);
            acc[j] = fmaf(sv.x, wv.x, acc[j]);
            acc[j] = fmaf(sv.y, wv.y, acc[j]);
            acc[j] = fmaf(sv.z, wv.z, acc[j]);
            acc[j] = fmaf(sv.w, wv.w, acc[j]);
        }
    }
    float mine = 0.0f;
    #pragma unroll
    for (int j = 0; j < 8; ++j) {
        float a = acc[j];
        #pragma unroll
        for (int off = 32; off; off >>= 1) a += __shfl_xor(a, off, 64);
        if (lane == j) mine = a;
    }
    if (lane < 8) {
        const int o = o0 + lane;
        const float cur = mine + bias[o];
        const int i4 = b * 512 + o;
        float m = mem4[i4];
        const float reset = (m > THR) ? 1.0f : 0.0f;
        m = BETA * m + cur - reset * THR;
        spk4[i4] = ((m - THR) > 0.0f) ? 1.0f : 0.0f;
        mem4[i4] = m;
    }
}

// ---------------------------------------------------------------------------
// cur5 = spk4 @ fc2_w.T + fc2_b; Leaky(mem5); writes spk_rec[t], mem_rec[t].
// ---------------------------------------------------------------------------
__global__ __launch_bounds__(256) void fc2_kernel(
    const float* __restrict__ spk4,
    const float* __restrict__ wt,
    const float* __restrict__ bias,
    float* __restrict__ mem5,
    float* __restrict__ out_spk,
    float* __restrict__ out_mem)
{
    const int wid = (blockIdx.x * 256 + threadIdx.x) >> 6;
    const int lane = threadIdx.x & 63;
    if (wid >= 2 * B_SZ) return;
    const int o = wid & 1;
    const int b = wid >> 1;
    const float* wr = wt + (size_t)o * 512;
    const float* sr = spk4 + (size_t)b * 512;
    float acc = 0.0f;
    #pragma unroll
    for (int i = 0; i < 8; ++i)
        acc = fmaf(sr[lane + i * 64], wr[lane + i * 64], acc);
    #pragma unroll
    for (int off = 32; off; off >>= 1) acc += __shfl_down(acc, off, 64);
    if (lane == 0) {
        const float cur = acc + bias[o];
        const int i5 = b * 2 + o;
        float m = mem5[i5];
        const float reset = (m > THR) ? 1.0f : 0.0f;
        m = BETA * m + cur - reset * THR;
        out_spk[i5] = ((m - THR) > 0.0f) ? 1.0f : 0.0f;
        out_mem[i5] = m;
        mem5[i5] = m;
    }
}

extern "C" void kernel_launch(void* const* d_in, const int* in_sizes, int n_in,
                              void* d_out, int out_size, void* d_ws, size_t ws_size,
                              hipStream_t stream) {
    (void)in_sizes; (void)n_in; (void)out_size; (void)ws_size;

    const float* x    = (const float*)d_in[0];
    const float* w1   = (const float*)d_in[1];
    const float* b1   = (const float*)d_in[2];
    const float* w2   = (const float*)d_in[3];
    const float* b2   = (const float*)d_in[4];
    const float* w3   = (const float*)d_in[5];
    const float* b3   = (const float*)d_in[6];
    const float* fc1w = (const float*)d_in[7];
    const float* fc1b = (const float*)d_in[8];
    const float* fc2w = (const float*)d_in[9];
    const float* fc2b = (const float*)d_in[10];

    float* out = (float*)d_out;
    float* ws = (float*)d_ws;

    const size_t N1 = (size_t)B_SZ * 16 * 16 * 128;
    const size_t N2 = (size_t)B_SZ * 32 * 8 * 64;
    const size_t N3 = (size_t)B_SZ * 64 * 4 * 32;

    size_t off = 0;
    float* syn1  = ws + off; off += N1;
    float* mem1a = ws + off; off += N1;
    float* mem1b = ws + off; off += N1;
    float* syn2  = ws + off; off += N2;
    float* mem2a = ws + off; off += N2;
    float* mem2b = ws + off; off += N2;
    float* syn3  = ws + off; off += N3;
    float* mem3a = ws + off; off += N3;
    float* mem3b = ws + off; off += N3;
    float* mem4  = ws + off; off += (size_t)B_SZ * 512;
    float* mem5  = ws + off; off += (size_t)B_SZ * 2;
    const size_t zero_elems = off;
    float* spk4 = ws + off; off += (size_t)B_SZ * 512;
    float* wr1  = ws + off; off += (size_t)4 * 16 * 17 * 9;
    float* wr2  = ws + off; off += (size_t)4 * 32 * 48 * 9;
    float* wr3  = ws + off; off += (size_t)4 * 64 * 96 * 9;

    hipMemsetAsync(d_ws, 0, zero_elems * sizeof(float), stream);

    repack_kernel<<<64, 256, 0, stream>>>(w1, wr1, 16, 17);
    repack_kernel<<<64, 256, 0, stream>>>(w2, wr2, 32, 48);
    repack_kernel<<<64, 256, 0, stream>>>(w3, wr3, 64, 96);

    float* m1r = mem1a; float* m1w = mem1b;
    float* m2r = mem2a; float* m2w = mem2b;
    float* m3r = mem3a; float* m3w = mem3b;

    for (int t = 0; t < T_STEPS; ++t) {
        const float* xt = x + (size_t)t * B_SZ * 16 * 128;

        // L1: R=1, CSPLIT=1, CHUNK=17 (1 round). grid 64*16 = 1024, LDS 26.3KB
        conv_lstm<1, 16, 16, 128, 1, 1, 17, false><<<1024, 256, 0, stream>>>(
            xt, m1r, syn1, syn1, m1w, wr1, b1);
        // L2: R=2, CSPLIT=4, CHUNK=24 (2 rounds). grid 64*4*4 = 1024, LDS 25.5KB
        conv_lstm<16, 32, 8, 64, 2, 4, 24, true><<<1024, 256, 0, stream>>>(
            m1w, m2r, syn2, syn2, m2w, wr2, b2);
        // L3: R=4, CSPLIT=16, CHUNK=32 (3 rounds). grid 64*16 = 1024, LDS 27KB
        conv_lstm<32, 64, 4, 32, 4, 16, 32, true><<<1024, 256, 0, stream>>>(
            m2w, m3r, syn3, syn3, m3w, wr3, b3);

        fc1_pool_kernel<<<1024, 256, 0, stream>>>(m3w, fc1w, fc1b, mem4, spk4);
        fc2_kernel<<<32, 256, 0, stream>>>(
            spk4, fc2w, fc2b, mem5, out + (size_t)t * 2 * B_SZ,
            out + 3200 + (size_t)t * 2 * B_SZ);

        float* tmp;
        tmp = m1r; m1r = m1w; m1w = tmp;
        tmp = m2r; m2r = m2w; m2w = tmp;
        tmp = m3r; m3r = m3w; m3w = tmp;
    }
}